// Round 5
// baseline (767.375 us; speedup 1.0000x reference)
//
#include <hip/hip_runtime.h>

// SimpleARRNN: GRU encoder (len<=512) + AR decoder (257 outputs). B=512, I=64, H=100, O=64. fp32.
// Fused affine input paths: W_c = W_ih@W_embed [300x64], b_c = W_ih@b_embed + b_ih
//                           W_d = W_c@W_proj   [300x100], b_d = W_c@b_proj + b_c
// rnn13 (R13): R12 single-barrier gate-in-quad + latency recovery.
// R12 post-mortem: spill fixed (WRITE 33MB), stall 413->281us, but VALU +50% and the
// sched_barrier(0) serialization re-exposed e1's ds_read latency -> net 840us > R8's 784.
// R13: (1) no sched_barrier; e1's LDS loads hoisted so both elements' reads are in
//          flight together (decoder: 14 ds_reads at phase start; encoder: e1 loads
//          issue under e0's gate transcendentals);
//      (2) wave 7 computes only d0..d3 in decoder (was 6 dots, used 4);
//      (3) hot-loop barrier = s_waitcnt lgkmcnt(0) + s_barrier (no vmcnt drain:
//          only LDS crosses waves; stores/prefetch loads stay in flight).
// Structure: quad q owns gate index q (Whh rows q,q+100,q+200 + input rows) -> DPP
// quad-reduce -> all 6 gate inputs in-register -> inline gate -> h' to double-buffered
// sh. ONE barrier per step. Unified weight file w[6][12]+w1[6]+b[6] for all waves
// (gate quads g<100; fake 100..111 zeros; proj quads 112..127 = Wproj rows k+16r).
// Decoder z stores delayed one step, issued at phase start.
// h layout: 4 chunks of 25 at stride 28 (bases at banks 0/28/24/20, broadcast reads).

#define B_  512
#define LC_ 512
#define I_  64
#define H_  100
#define O_  64
#define T_  256
#define H3  300

// ws float offsets
#define WS_WC   0        // [300][64]
#define WS_BC   19200    // [300]
#define WS_WD   19500    // [300][100]
#define WS_BD   49500    // [300]
#define WS_PERM 49800    // int[512]

typedef float v2f __attribute__((ext_vector_type(2)));

__global__ __launch_bounds__(64) void prep1(const float* __restrict__ Wih,
                                            const float* __restrict__ bih,
                                            const float* __restrict__ Wemb,
                                            const float* __restrict__ bemb,
                                            float* __restrict__ ws) {
    int j = blockIdx.x;   // 0..299
    int i = threadIdx.x;  // 0..63
    float acc = 0.f;
    for (int k = 0; k < H_; ++k) acc += Wih[j * H_ + k] * Wemb[k * I_ + i];
    ws[WS_WC + j * I_ + i] = acc;
    if (i == 0) {
        float b = bih[j];
        for (int k = 0; k < H_; ++k) b += Wih[j * H_ + k] * bemb[k];
        ws[WS_BC + j] = b;
    }
}

__global__ __launch_bounds__(128) void prep2(const float* __restrict__ Wproj,
                                             const float* __restrict__ bproj,
                                             float* __restrict__ ws) {
    int j = blockIdx.x;   // 0..299
    int u = threadIdx.x;
    const float* Wc = ws + WS_WC;
    if (u < H_) {
        float acc = 0.f;
        for (int o = 0; o < O_; ++o) acc += Wc[j * I_ + o] * Wproj[o * H_ + u];
        ws[WS_WD + j * H_ + u] = acc;
    }
    if (u == 0) {
        float b = ws[WS_BC + j];
        for (int o = 0; o < O_; ++o) b += Wc[j * I_ + o] * bproj[o];
        ws[WS_BD + j] = b;
    }
}

// rank elements by length descending -> perm (longest first)
__global__ __launch_bounds__(512) void sortk(const int* __restrict__ lens,
                                             int* __restrict__ perm) {
    __shared__ int sl[B_];
    int tid = threadIdx.x;
    sl[tid] = lens[tid];
    __syncthreads();
    int li = sl[tid];
    int rank = 0;
    for (int j = 0; j < B_; ++j) {
        int lj = sl[j];
        rank += (lj > li) || (lj == li && j < tid);
    }
    perm[rank] = tid;
}

__device__ __forceinline__ float sigm_(float x) { return 1.f / (1.f + __expf(-x)); }
__device__ __forceinline__ float tanh_(float x) {
    float t = __expf(-2.f * fabsf(x));
    float r = (1.f - t) / (1.f + t);
    return (x >= 0.f) ? r : -r;
}

template <int CTRL>
__device__ __forceinline__ float dppmov_(float x) {
    return __int_as_float(
        __builtin_amdgcn_mov_dpp(__float_as_int(x), CTRL, 0xF, 0xF, true));
}
// reduce across the 4 lanes of a quad; all 4 lanes end with the sum
__device__ __forceinline__ float red4_(float a) {
    a += dppmov_<0xB1>(a);    // quad_perm [1,0,3,2] = xor1 (involution, verified R5/R7)
    a += dppmov_<0x4E>(a);    // quad_perm [2,3,0,1] = xor2
    return a;
}

// h-row dot: 12 v2f pairs + tail scalar (25 cols), then quad reduce
__device__ __forceinline__ float dotH_(const v2f* __restrict__ w2, float w1,
                                       const v2f* __restrict__ hv2, float h24) {
    v2f a = {0.f, 0.f};
    #pragma unroll
    for (int j = 0; j < 12; ++j) a = w2[j] * hv2[j] + a;   // v_pk_fma_f32
    return red4_(fmaf(w1, h24, a.x + a.y));
}
// ctx-row dot: 8 v2f pairs (16 cols), then quad reduce
__device__ __forceinline__ float dotC_(const v2f* __restrict__ w2,
                                       const v2f* __restrict__ cv2) {
    v2f a = {0.f, 0.f};
    #pragma unroll
    for (int j = 0; j < 8; ++j) a = w2[j] * cv2[j] + a;
    return red4_(a.x + a.y);
}

// hot-loop barrier: only LDS data crosses waves -> drain lgkm only, not vmcnt
__device__ __forceinline__ void barrier_lgkm_() {
    asm volatile("s_waitcnt lgkmcnt(0)\n\ts_barrier" ::: "memory");
}

__global__ __attribute__((amdgpu_flat_work_group_size(512, 512)))
__attribute__((amdgpu_waves_per_eu(2, 2)))
void rnn13(const float* __restrict__ ctx, const int* __restrict__ lens,
           const float* __restrict__ Whh, const float* __restrict__ bhh,
           const float* __restrict__ Wproj, const float* __restrict__ bproj,
           const float* __restrict__ ws, float* __restrict__ out) {

    const int tid = threadIdx.x;
    const int l   = tid & 3;          // quad lane: h-cols 25l..25l+24, ctx-cols 16l..16l+15
    const int g   = tid >> 2;         // quad index 0..127
    const bool wl = (l == 0);

    const int* perm = (const int*)(ws + WS_PERM);
    const int e0 = perm[blockIdx.x];         // long element
    const int e1 = perm[511 - blockIdx.x];   // short element
    const int len0 = lens[e0], len1 = lens[e1];

    __shared__ __align__(16) float sh[2][2][112];    // [elem][buf][4 chunks of 25 @ stride 28]
    __shared__ __align__(16) float sctx[2][2][64];   // [elem][buf][64]

    const bool isG  = (g < 112);      // gate quads (waves 0..6); wave 7 = proj/prefetch
    const bool real = (g < 100);      // fake gate indices 100..111: zero weights, no write
    const int  hslot = real ? (28 * (g / 25) + (g % 25)) : 0;

    // ---- UNIFIED register-resident weight file (identical shape for every thread) ----
    v2f   w[6][12]; float w1[6]; float b[6];
    float hreg0 = 0.f, hreg1 = 0.f;   // gate quads: own h | proj quads: unused
    float zs0 = 0.f, zs1 = 0.f;       // proj quads: delayed z store

    #pragma unroll
    for (int r = 0; r < 6; ++r) {
        #pragma unroll
        for (int j = 0; j < 12; ++j) w[r][j] = v2f{0.f, 0.f};
        w1[r] = 0.f; b[r] = 0.f;
    }
    if (real) {   // gate quads: Whh rows + Wc rows (enc input path)
        #pragma unroll
        for (int r = 0; r < 3; ++r) {
            const float* p = Whh + (g + 100 * r) * H_ + 25 * l;
            #pragma unroll
            for (int j = 0; j < 12; ++j) w[r][j] = v2f{p[2 * j], p[2 * j + 1]};
            w1[r] = p[24];
            b[r]  = bhh[g + 100 * r];
            const float* pc = ws + WS_WC + (g + 100 * r) * I_ + 16 * l;
            #pragma unroll
            for (int j = 0; j < 8; ++j) w[3 + r][j] = v2f{pc[2 * j], pc[2 * j + 1]};
            b[3 + r] = ws[WS_BC + g + 100 * r];
        }
    } else if (!isG) {   // proj quads: Wproj rows k+16r in w[0..3]
        const int k = g - 112;
        #pragma unroll
        for (int r = 0; r < 4; ++r) {
            const float* p = Wproj + (k + 16 * r) * H_ + 25 * l;
            #pragma unroll
            for (int j = 0; j < 12; ++j) w[r][j] = v2f{p[2 * j], p[2 * j + 1]};
            w1[r] = p[24];
            b[r]  = bproj[k + 16 * r];
        }
    }

    // ---- prefetch lanes (wave 7): lanes 0..15 -> e0, 16..31 -> e1 ----
    const int pl = tid - 448;
    const int pe = (pl >> 4) & 1;
    const int pi = pl & 15;
    const float4* pc0 = (const float4*)(ctx + (size_t)e0 * LC_ * I_);
    const float4* pc1 = (const float4*)(ctx + (size_t)e1 * LC_ * I_);
    const float4* pcm = pe ? pc1 : pc0;
    const int lenp = pe ? len1 : len0;
    float4 pf = {0.f, 0.f, 0.f, 0.f};

    float* oute0 = out + (size_t)e0 * (T_ + 1) * O_;
    float* oute1 = out + (size_t)e1 * (T_ + 1) * O_;

    // ---- init: zero both h buffers; stage ctx[0] and prefetch ctx[1] ----
    if (tid < 448) ((float*)sh)[tid] = 0.f;
    if (!isG && pl < 32) {
        *(float4*)&sctx[pe][0][4 * pi] = pcm[pi];
        if (1 < lenp) pf = pcm[16 + pi];
    }
    __syncthreads();

    // ---- loaders ----
    auto loadH = [&](int e, int bf, v2f* hv2, float& h24) {
        #pragma unroll
        for (int q = 0; q < 6; ++q) {
            float4 f = *(const float4*)&sh[e][bf][28 * l + 4 * q];
            hv2[2 * q]     = v2f{f.x, f.y};
            hv2[2 * q + 1] = v2f{f.z, f.w};
        }
        h24 = sh[e][bf][28 * l + 24];
    };
    auto loadC = [&](int e, int bf, v2f* cv2) {
        #pragma unroll
        for (int q = 0; q < 4; ++q) {
            float4 f = *(const float4*)&sctx[e][bf][16 * l + 4 * q];
            cv2[2 * q]     = v2f{f.x, f.y};
            cv2[2 * q + 1] = v2f{f.z, f.w};
        }
    };

    // ================ encoder: t = 0 .. len0-1 (one barrier per step) ================
    for (int t = 0; t < len0; ++t) {
        const int rb = t & 1, wb = rb ^ 1;
        const bool live1 = (t < len1);   // block-uniform
        if (isG) {
            // e0 loads + dots
            v2f hv0[12]; float h240; loadH(0, rb, hv0, h240);
            v2f cv0[8];  loadC(0, rb, cv0);
            float d0 = dotH_(w[0], w1[0], hv0, h240) + b[0];
            float d1 = dotH_(w[1], w1[1], hv0, h240) + b[1];
            float d2 = dotH_(w[2], w1[2], hv0, h240) + b[2];
            float d3 = dotC_(w[3], cv0) + b[3];
            float d4 = dotC_(w[4], cv0) + b[4];
            float d5 = dotC_(w[5], cv0) + b[5];
            // e1 loads issue here; latency hides under e0's gate transcendentals
            v2f hv1[12]; float h241; v2f cv1[8];
            if (live1) { loadH(1, rb, hv1, h241); loadC(1, rb, cv1); }
            {   // e0 gate
                float r = sigm_(d3 + d0);
                float z = sigm_(d4 + d1);
                float n = tanh_(d5 + r * d2);
                hreg0 = (1.f - z) * n + z * hreg0;
                if (wl && real) sh[0][wb][hslot] = hreg0;
            }
            if (live1) {
                float e0d = dotH_(w[0], w1[0], hv1, h241) + b[0];
                float e1d = dotH_(w[1], w1[1], hv1, h241) + b[1];
                float e2d = dotH_(w[2], w1[2], hv1, h241) + b[2];
                float e3d = dotC_(w[3], cv1) + b[3];
                float e4d = dotC_(w[4], cv1) + b[4];
                float e5d = dotC_(w[5], cv1) + b[5];
                float r = sigm_(e3d + e0d);
                float z = sigm_(e4d + e1d);
                float n = tanh_(e5d + r * e2d);
                hreg1 = (1.f - z) * n + z * hreg1;
                if (wl && real) sh[1][wb][hslot] = hreg1;
            }
        } else if (pl < 32) {   // wave 7: ctx prefetch (write t+1, load t+2)
            if (t + 1 < lenp) *(float4*)&sctx[pe][wb][4 * pi] = pf;
            if (t + 2 < lenp) pf = pcm[(t + 2) * 16 + pi];
        }
        barrier_lgkm_();
    }

    // ---- switch gate input path to decoder: Wd rows + bd (registers only) ----
    if (real) {
        #pragma unroll
        for (int r = 0; r < 3; ++r) {
            const float* p = ws + WS_WD + (g + 100 * r) * H_ + 25 * l;
            #pragma unroll
            for (int j = 0; j < 12; ++j) w[3 + r][j] = v2f{p[2 * j], p[2 * j + 1]};
            w1[3 + r] = p[24];
            b[3 + r]  = ws[WS_BD + g + 100 * r];
        }
    }

    // ================ decoder: outputs t = 0..256 (one barrier per step) ================
    const int p0 = len0 & 1, p1 = len1 & 1;   // h parity at decoder entry
    for (int t = 0; t <= T_; ++t) {
        const int rb0 = (p0 + t) & 1, rb1 = (p1 + t) & 1;
        // proj quads: store PREVIOUS step's z at phase start (ack hides under dots)
        if (!isG && t >= 1) {
            const int k = g - 112;
            oute0[(t - 1) * O_ + k + 16 * l] = zs0;
            oute1[(t - 1) * O_ + k + 16 * l] = zs1;
        }
        if (t < T_ || !isG) {   // gate quads skip last iter (h_{T+1} unneeded)
            // both elements' h reads in flight together
            v2f hv0[12]; float h240; loadH(0, rb0, hv0, h240);
            v2f hv1[12]; float h241; loadH(1, rb1, hv1, h241);
            {   // e0
                float d0 = dotH_(w[0], w1[0], hv0, h240) + b[0];
                float d1 = dotH_(w[1], w1[1], hv0, h240) + b[1];
                float d2 = dotH_(w[2], w1[2], hv0, h240) + b[2];
                float d3 = dotH_(w[3], w1[3], hv0, h240) + b[3];
                if (isG) {
                    float d4 = dotH_(w[4], w1[4], hv0, h240) + b[4];
                    float d5 = dotH_(w[5], w1[5], hv0, h240) + b[5];
                    float r = sigm_(d3 + d0);
                    float z = sigm_(d4 + d1);
                    float n = tanh_(d5 + r * d2);
                    hreg0 = (1.f - z) * n + z * hreg0;
                    if (wl && real) sh[0][rb0 ^ 1][hslot] = hreg0;
                } else {
                    zs0 = (l == 0) ? d0 : (l == 1) ? d1 : (l == 2) ? d2 : d3;
                }
            }
            {   // e1
                float d0 = dotH_(w[0], w1[0], hv1, h241) + b[0];
                float d1 = dotH_(w[1], w1[1], hv1, h241) + b[1];
                float d2 = dotH_(w[2], w1[2], hv1, h241) + b[2];
                float d3 = dotH_(w[3], w1[3], hv1, h241) + b[3];
                if (isG) {
                    float d4 = dotH_(w[4], w1[4], hv1, h241) + b[4];
                    float d5 = dotH_(w[5], w1[5], hv1, h241) + b[5];
                    float r = sigm_(d3 + d0);
                    float z = sigm_(d4 + d1);
                    float n = tanh_(d5 + r * d2);
                    hreg1 = (1.f - z) * n + z * hreg1;
                    if (wl && real) sh[1][rb1 ^ 1][hslot] = hreg1;
                } else {
                    zs1 = (l == 0) ? d0 : (l == 1) ? d1 : (l == 2) ? d2 : d3;
                }
            }
        }
        barrier_lgkm_();
    }
    // drain: final outputs (t = T_)
    if (!isG) {
        const int k = g - 112;
        oute0[T_ * O_ + k + 16 * l] = zs0;
        oute1[T_ * O_ + k + 16 * l] = zs1;
    }
}

extern "C" void kernel_launch(void* const* d_in, const int* in_sizes, int n_in,
                              void* d_out, int out_size, void* d_ws, size_t ws_size,
                              hipStream_t stream) {
    (void)in_sizes; (void)n_in; (void)out_size; (void)ws_size;
    const float* ctx  = (const float*)d_in[0];
    const int*   lens = (const int*)d_in[1];
    // d_in[2] = t_steps (256, hardcoded)
    const float* Wemb = (const float*)d_in[3];
    const float* bemb = (const float*)d_in[4];
    const float* Wih  = (const float*)d_in[5];
    const float* bih  = (const float*)d_in[6];
    const float* Whh  = (const float*)d_in[7];
    const float* bhh  = (const float*)d_in[8];
    const float* Wpr  = (const float*)d_in[9];
    const float* bpr  = (const float*)d_in[10];
    float* ws  = (float*)d_ws;
    float* out = (float*)d_out;

    prep1<<<H3, 64, 0, stream>>>(Wih, bih, Wemb, bemb, ws);
    prep2<<<H3, 128, 0, stream>>>(Wpr, bpr, ws);
    sortk<<<1, 512, 0, stream>>>(lens, (int*)(ws + WS_PERM));
    rnn13<<<256, 512, 0, stream>>>(ctx, lens, Whh, bhh, Wpr, bpr, ws, out);
}

// Round 6
// 746.211 us; speedup vs baseline: 1.0284x; 1.0284x over previous
//
#include <hip/hip_runtime.h>

// SimpleARRNN: GRU encoder (len<=512) + AR decoder (257 outputs). B=512, I=64, H=100, O=64. fp32.
// Fused affine input paths: W_c = W_ih@W_embed [300x64], b_c = W_ih@b_embed + b_ih
//                           W_d = W_c@W_proj   [300x100], b_d = W_c@b_proj + b_c
// rnn14 (R14): R8 trunk (best: 784us prof / 729 harness) + the two overhead removals
// that R12/R13 proved safe, with NO structural change:
//  (a) hot-loop barriers are s_waitcnt lgkmcnt(0) + s_barrier (no vmcnt(0) drain).
//      R8's __syncthreads drained prefetch loads / output stores at EVERY barrier,
//      putting HBM ack latency on the all-wave critical path.
//  (b) decoder out-store delayed one step: z_t read from sdot into a register in the
//      gate phase, stored to global at the START of step t+1's dot phase.
// R13 post-mortem pinned the regime: steps are latency/serial-chain bound, not
// issue-bound (E1 steps cost = E2 steps) -> the lean-issue R8 structure wins; the
// gate-in-quad branch (R10-R13, +50% VALU for -1 barrier) is abandoned.
// rnn8 structure: 2 elements/block (long+short pair, length-sorted), 256 blocks x 512
// threads, waves_per_eu(2,2). 4-lane row split (l=tid&3 owns h-cols 25l..25l+24,
// ctx-cols 16l..16l+15), register-resident weights w2[6][12] (unified file, all waves),
// 6 passes, slot = 128p + g; DPP quad_perm xor1+xor2 reduce; lane l==0 stores sdot.
// h in LDS: 4 chunks of 25 at stride 28 (banks 0/28/24/20 per beat - disjoint).

#define B_  512
#define LC_ 512
#define I_  64
#define H_  100
#define O_  64
#define T_  256
#define H3  300

// ws float offsets
#define WS_WC   0        // [300][64]
#define WS_BC   19200    // [300]
#define WS_WD   19500    // [300][100]
#define WS_BD   49500    // [300]
#define WS_PERM 49800    // int[512]

typedef float v2f __attribute__((ext_vector_type(2)));

__global__ __launch_bounds__(64) void prep1(const float* __restrict__ Wih,
                                            const float* __restrict__ bih,
                                            const float* __restrict__ Wemb,
                                            const float* __restrict__ bemb,
                                            float* __restrict__ ws) {
    int j = blockIdx.x;   // 0..299
    int i = threadIdx.x;  // 0..63
    float acc = 0.f;
    for (int k = 0; k < H_; ++k) acc += Wih[j * H_ + k] * Wemb[k * I_ + i];
    ws[WS_WC + j * I_ + i] = acc;
    if (i == 0) {
        float b = bih[j];
        for (int k = 0; k < H_; ++k) b += Wih[j * H_ + k] * bemb[k];
        ws[WS_BC + j] = b;
    }
}

__global__ __launch_bounds__(128) void prep2(const float* __restrict__ Wproj,
                                             const float* __restrict__ bproj,
                                             float* __restrict__ ws) {
    int j = blockIdx.x;   // 0..299
    int u = threadIdx.x;
    const float* Wc = ws + WS_WC;
    if (u < H_) {
        float acc = 0.f;
        for (int o = 0; o < O_; ++o) acc += Wc[j * I_ + o] * Wproj[o * H_ + u];
        ws[WS_WD + j * H_ + u] = acc;
    }
    if (u == 0) {
        float b = ws[WS_BC + j];
        for (int o = 0; o < O_; ++o) b += Wc[j * I_ + o] * bproj[o];
        ws[WS_BD + j] = b;
    }
}

// rank elements by length descending -> perm (longest first)
__global__ __launch_bounds__(512) void sortk(const int* __restrict__ lens,
                                             int* __restrict__ perm) {
    __shared__ int sl[B_];
    int tid = threadIdx.x;
    sl[tid] = lens[tid];
    __syncthreads();
    int li = sl[tid];
    int rank = 0;
    for (int j = 0; j < B_; ++j) {
        int lj = sl[j];
        rank += (lj > li) || (lj == li && j < tid);
    }
    perm[rank] = tid;
}

__device__ __forceinline__ float sigm_(float x) { return 1.f / (1.f + __expf(-x)); }
__device__ __forceinline__ float tanh_(float x) {
    float t = __expf(-2.f * fabsf(x));
    float r = (1.f - t) / (1.f + t);
    return (x >= 0.f) ? r : -r;
}

template <int CTRL>
__device__ __forceinline__ float dppmov_(float x) {
    return __int_as_float(
        __builtin_amdgcn_mov_dpp(__float_as_int(x), CTRL, 0xF, 0xF, true));
}
// reduce across the 4 lanes of a quad (row group); all 4 lanes end with the sum
__device__ __forceinline__ float red4_(float a) {
    a += dppmov_<0xB1>(a);    // quad_perm [1,0,3,2] = xor1 (involution, verified R5/R7)
    a += dppmov_<0x4E>(a);    // quad_perm [2,3,0,1] = xor2
    return a;
}

// h-row dot: 12 v2f pairs + tail scalar (25 cols), then quad reduce
__device__ __forceinline__ float dotH_(const v2f* __restrict__ w2, float w1,
                                       const v2f* __restrict__ hv2, float h24) {
    v2f a = {0.f, 0.f};
    #pragma unroll
    for (int j = 0; j < 12; ++j) a = w2[j] * hv2[j] + a;   // v_pk_fma_f32
    return red4_(fmaf(w1, h24, a.x + a.y));
}
// ctx-row dot: 8 v2f pairs (16 cols), then quad reduce
__device__ __forceinline__ float dotC_(const v2f* __restrict__ w2,
                                       const v2f* __restrict__ cv2) {
    v2f a = {0.f, 0.f};
    #pragma unroll
    for (int j = 0; j < 8; ++j) a = w2[j] * cv2[j] + a;
    return red4_(a.x + a.y);
}

// hot-loop barrier: only LDS data crosses waves -> drain lgkm only, not vmcnt.
// Global prefetch loads / delayed output stores stay in flight across the barrier
// (their own data deps get compiler-inserted vmcnt waits at the point of use).
__device__ __forceinline__ void barrier_lgkm_() {
    asm volatile("s_waitcnt lgkmcnt(0)\n\ts_barrier" ::: "memory");
}

__global__ __attribute__((amdgpu_flat_work_group_size(512, 512)))
__attribute__((amdgpu_waves_per_eu(2, 2)))
void rnn14(const float* __restrict__ ctx, const int* __restrict__ lens,
           const float* __restrict__ Whh, const float* __restrict__ bhh,
           const float* __restrict__ Wproj, const float* __restrict__ bproj,
           const float* __restrict__ ws, float* __restrict__ out) {

    const int tid = threadIdx.x;
    const int l   = tid & 3;          // quad lane: h-cols 25l.., ctx-cols 16l..
    const int g   = tid >> 2;         // 0..127 row-group
    const bool wl = (l == 0);

    const int* perm = (const int*)(ws + WS_PERM);
    const int e0 = perm[blockIdx.x];         // long element
    const int e1 = perm[511 - blockIdx.x];   // short element
    const int len0 = lens[e0], len1 = lens[e1];

    __shared__ __align__(16) float sh[2][112];    // h: 4 chunks of 25, stride 28
    __shared__ __align__(16) float sctx[2][64];
    __shared__ float sdot[2][672];                // gh 0..299 | xi 300..599 | proj 600..663
    __shared__ float sbh[H3], sbx[H3];

    // ---- per-pass config: slot = 128p + g ----
    const bool p2hh = (g < 44);      // pass2: slot 256..299 -> Whh, else input-path row g-44
    const bool p4a  = (g < 88);      // pass4 enc: Wc row 212+g; dec: Wd row 212+g (else Wproj)
    const bool p5a  = (g < 24);      // pass5 dec only: Wproj row 40+g

    // ---- register-resident weights: 6 passes x (12 v2f + tail) ----
    v2f   w2[6][12];
    float w1[6];
    {
        const float* r0 = Whh + g * H_ + 25 * l;
        const float* r1 = Whh + (128 + g) * H_ + 25 * l;
        #pragma unroll
        for (int j = 0; j < 12; ++j) {
            w2[0][j] = v2f{r0[2 * j], r0[2 * j + 1]};
            w2[1][j] = v2f{r1[2 * j], r1[2 * j + 1]};
        }
        w1[0] = r0[24]; w1[1] = r1[24];
        if (p2hh) {
            const float* r2 = Whh + (256 + g) * H_ + 25 * l;
            #pragma unroll
            for (int j = 0; j < 12; ++j) w2[2][j] = v2f{r2[2 * j], r2[2 * j + 1]};
            w1[2] = r2[24];
        } else {
            const float* r2 = ws + WS_WC + (g - 44) * I_ + 16 * l;
            #pragma unroll
            for (int j = 0; j < 8; ++j) w2[2][j] = v2f{r2[2 * j], r2[2 * j + 1]};
        }
        const float* r3 = ws + WS_WC + (84 + g) * I_ + 16 * l;
        #pragma unroll
        for (int j = 0; j < 8; ++j) w2[3][j] = v2f{r3[2 * j], r3[2 * j + 1]};
        if (p4a) {
            const float* r4 = ws + WS_WC + (212 + g) * I_ + 16 * l;
            #pragma unroll
            for (int j = 0; j < 8; ++j) w2[4][j] = v2f{r4[2 * j], r4[2 * j + 1]};
        }
    }

    // ---- roles (same as R8) ----
    const int ge = (tid >= 100);                 // gate threads: tid<200
    const int gi = tid - (ge ? 100 : 0);
    const int hs = 28 * (gi / 25) + (gi % 25);   // h slot in 28-stride chunks
    const int lenG = ge ? len1 : len0;
    float hreg = 0.f;

    const int oe = (tid >> 6) & 1;               // out threads: tid in [256,384)
    const int oo = tid & 63;
    float* oute = out + (size_t)(oe ? e1 : e0) * (T_ + 1) * O_;
    float bpr = 0.f;
    if (tid >= 256 && tid < 384) bpr = bproj[oo];

    const int pe = (tid >> 4) & 1;               // prefetch threads: tid in [384,416)
    const int pi = tid & 15;
    const float4* pctx = (const float4*)(ctx + (size_t)(pe ? e1 : e0) * LC_ * I_);
    const int lenP = pe ? len1 : len0;

    // ---- init ----
    if (tid < 224) ((float*)sh)[tid] = 0.f;
    if (tid < H3) { sbh[tid] = bhh[tid]; sbx[tid] = (ws + WS_BC)[tid]; }
    if (tid >= 384 && tid < 416) *(float4*)&sctx[pe][4 * pi] = pctx[pi];   // t=0
    __syncthreads();

    // ================ encoder: t = 0 .. len0-1 (len0 >= len1) ================
    for (int t = 0; t < len0; ++t) {
        float4 pf;
        const bool hp = (tid >= 384 && tid < 416) && (t + 1 < lenP);
        if (hp) pf = pctx[(t + 1) * 16 + pi];

        #pragma unroll
        for (int e = 0; e < 2; ++e) {
            if (e == 0 || t < len1) {       // block-uniform skip of finished element
                v2f hv2[12], cv2[8];
                float h24;
                #pragma unroll
                for (int q = 0; q < 6; ++q) {
                    float4 f = *(const float4*)&sh[e][28 * l + 4 * q];
                    hv2[2 * q]     = v2f{f.x, f.y};
                    hv2[2 * q + 1] = v2f{f.z, f.w};
                }
                h24 = sh[e][28 * l + 24];
                #pragma unroll
                for (int q = 0; q < 4; ++q) {
                    float4 f = *(const float4*)&sctx[e][16 * l + 4 * q];
                    cv2[2 * q]     = v2f{f.x, f.y};
                    cv2[2 * q + 1] = v2f{f.z, f.w};
                }

                float a0 = dotH_(w2[0], w1[0], hv2, h24);
                float a1 = dotH_(w2[1], w1[1], hv2, h24);
                float a2 = p2hh ? dotH_(w2[2], w1[2], hv2, h24) : dotC_(w2[2], cv2);
                float a3 = dotC_(w2[3], cv2);
                if (wl) {
                    sdot[e][g] = a0;
                    sdot[e][128 + g] = a1;
                    sdot[e][256 + g] = a2;
                    sdot[e][384 + g] = a3;
                }
                if (p4a) {
                    float a4 = dotC_(w2[4], cv2);
                    if (wl) sdot[e][512 + g] = a4;
                }
            }
        }
        barrier_lgkm_();
        if (tid < 200 && t < lenG) {
            const float* sd = sdot[ge];
            float gr = sd[gi]       + sbh[gi];
            float gz = sd[gi + 100] + sbh[gi + 100];
            float gn = sd[gi + 200] + sbh[gi + 200];
            float xr = sd[gi + 300] + sbx[gi];
            float xz = sd[gi + 400] + sbx[gi + 100];
            float xn = sd[gi + 500] + sbx[gi + 200];
            float r = sigm_(xr + gr);
            float z = sigm_(xz + gz);
            float n = tanh_(xn + r * gn);
            hreg = (1.f - z) * n + z * hreg;
            sh[ge][hs] = hreg;
        }
        if (hp) *(float4*)&sctx[pe][4 * pi] = pf;
        barrier_lgkm_();
    }

    // ---- switch input-path weights to decoder: Wd (+Wproj rows), bc -> bd ----
    {
        if (!p2hh) {
            const float* r2 = ws + WS_WD + (g - 44) * H_ + 25 * l;
            #pragma unroll
            for (int j = 0; j < 12; ++j) w2[2][j] = v2f{r2[2 * j], r2[2 * j + 1]};
            w1[2] = r2[24];
        }
        const float* r3 = ws + WS_WD + (84 + g) * H_ + 25 * l;
        #pragma unroll
        for (int j = 0; j < 12; ++j) w2[3][j] = v2f{r3[2 * j], r3[2 * j + 1]};
        w1[3] = r3[24];
        const float* r4 = p4a ? (ws + WS_WD + (212 + g) * H_ + 25 * l)
                              : (Wproj + (g - 88) * H_ + 25 * l);
        #pragma unroll
        for (int j = 0; j < 12; ++j) w2[4][j] = v2f{r4[2 * j], r4[2 * j + 1]};
        w1[4] = r4[24];
        if (p5a) {
            const float* r5 = Wproj + (40 + g) * H_ + 25 * l;
            #pragma unroll
            for (int j = 0; j < 12; ++j) w2[5][j] = v2f{r5[2 * j], r5[2 * j + 1]};
            w1[5] = r5[24];
        }
    }
    if (tid < H3) sbx[tid] = (ws + WS_BD)[tid];
    // safe: sbx next read only after the decoder's first barrier

    // ================ decoder: outputs t = 0..256 ================
    float zs = 0.f;   // out threads: previous step's z (delayed store)
    for (int t = 0; t <= T_; ++t) {
        // delayed store of z_{t-1}: issued at phase start, ack hides under dots;
        // lgkm-only barriers never force a drain of this store.
        if (tid >= 256 && tid < 384 && t >= 1) {
            oute[(t - 1) * O_ + oo] = zs;
        }
        #pragma unroll
        for (int e = 0; e < 2; ++e) {
            v2f hv2[12];
            float h24;
            #pragma unroll
            for (int q = 0; q < 6; ++q) {
                float4 f = *(const float4*)&sh[e][28 * l + 4 * q];
                hv2[2 * q]     = v2f{f.x, f.y};
                hv2[2 * q + 1] = v2f{f.z, f.w};
            }
            h24 = sh[e][28 * l + 24];

            float a0 = dotH_(w2[0], w1[0], hv2, h24);
            float a1 = dotH_(w2[1], w1[1], hv2, h24);
            float a2 = dotH_(w2[2], w1[2], hv2, h24);
            float a3 = dotH_(w2[3], w1[3], hv2, h24);
            float a4 = dotH_(w2[4], w1[4], hv2, h24);
            if (wl) {
                sdot[e][g] = a0;
                sdot[e][128 + g] = a1;
                sdot[e][256 + g] = a2;
                sdot[e][384 + g] = a3;
                sdot[e][512 + g] = a4;
            }
            if (p5a) {
                float a5 = dotH_(w2[5], w1[5], hv2, h24);
                if (wl) sdot[e][640 + g] = a5;
            }
        }
        barrier_lgkm_();
        if (tid >= 256 && tid < 384) {
            zs = sdot[oe][600 + oo] + bpr;   // read now, store next phase
        }
        if (t == T_) break;   // uniform
        if (tid < 200) {
            const float* sd = sdot[ge];
            float gr = sd[gi]       + sbh[gi];
            float gz = sd[gi + 100] + sbh[gi + 100];
            float gn = sd[gi + 200] + sbh[gi + 200];
            float xr = sd[gi + 300] + sbx[gi];
            float xz = sd[gi + 400] + sbx[gi + 100];
            float xn = sd[gi + 500] + sbx[gi + 200];
            float r = sigm_(xr + gr);
            float z = sigm_(xz + gz);
            float n = tanh_(xn + r * gn);
            hreg = (1.f - z) * n + z * hreg;
            sh[ge][hs] = hreg;
        }
        barrier_lgkm_();
    }
    // drain: final outputs (t = T_)
    if (tid >= 256 && tid < 384) {
        oute[T_ * O_ + oo] = zs;
    }
}

extern "C" void kernel_launch(void* const* d_in, const int* in_sizes, int n_in,
                              void* d_out, int out_size, void* d_ws, size_t ws_size,
                              hipStream_t stream) {
    (void)in_sizes; (void)n_in; (void)out_size; (void)ws_size;
    const float* ctx  = (const float*)d_in[0];
    const int*   lens = (const int*)d_in[1];
    // d_in[2] = t_steps (256, hardcoded)
    const float* Wemb = (const float*)d_in[3];
    const float* bemb = (const float*)d_in[4];
    const float* Wih  = (const float*)d_in[5];
    const float* bih  = (const float*)d_in[6];
    const float* Whh  = (const float*)d_in[7];
    const float* bhh  = (const float*)d_in[8];
    const float* Wpr  = (const float*)d_in[9];
    const float* bpr  = (const float*)d_in[10];
    float* ws  = (float*)d_ws;
    float* out = (float*)d_out;

    prep1<<<H3, 64, 0, stream>>>(Wih, bih, Wemb, bemb, ws);
    prep2<<<H3, 128, 0, stream>>>(Wpr, bpr, ws);
    sortk<<<1, 512, 0, stream>>>(lens, (int*)(ws + WS_PERM));
    rnn14<<<256, 512, 0, stream>>>(ctx, lens, Whh, bhh, Wpr, bpr, ws, out);
}